// Round 1
// baseline (2861.199 us; speedup 1.0000x reference)
//
#include <hip/hip_runtime.h>
#include <hip/hip_bf16.h>
#include <cmath>

#define NCH 117   // 9*13
#define NLEV 13

struct Consts {
  float lo[9];
  float inv[9];
  float w[11];
};

static Consts make_consts() {
  static const double rmin[9] = {170.0, 85000.0, -110.0, -80.0, 170.0, 0.0, -110.0, -100.0, -1000.0};
  static const double rmax[9] = {350.0, 110000.0, 110.0, 80.0, 350.0, 0.04, 110.0, 100.0, 60000.0};
  Consts c;
  for (int i = 0; i < 9; ++i) {
    float lo = (float)rmin[i];
    float hi = (float)rmax[i];
    float span = hi - lo;
    c.lo[i] = lo;
    c.inv[i] = (float)(1.0 / (double)span);
  }
  double g[11], s = 0.0;
  for (int k = 0; k < 11; ++k) {
    double d = (double)k - 5.0;
    g[k] = std::exp(-d * d / 4.5);
    s += g[k];
  }
  for (int k = 0; k < 11; ++k) c.w[k] = (float)(g[k] / s);
  return c;
}

// ---------------------------------------------------------------------------
// Kernel 1: fused pixel-loss partial sums + first 2x2 avg-pool (scale0->1).
// One thread per scale-1 pixel. Window i covers input rows {2i-1, 2i} (row -1
// is the zero pad from jax reduce_window padding=(1,1) on odd H), cols
// {2j, 2j+1}. Union over threads covers every input pixel exactly once, so
// pixel-loss partials accumulated here see each element once.
// ---------------------------------------------------------------------------
__global__ __launch_bounds__(256)
void k_pool0(const float* __restrict__ x, const float* __restrict__ y,
             __hip_bfloat16* __restrict__ px, __hip_bfloat16* __restrict__ py,
             float2* __restrict__ part, Consts cst)
{
  const int H = 721, W = 1440, Hp = 361, Wp = 720;
  int idx = blockIdx.x * 256 + threadIdx.x;
  const int total = NCH * Hp * Wp;
  float s1 = 0.f, s2 = 0.f;
  if (idx < total) {
    int nc  = idx / (Hp * Wp);
    int rem = idx - nc * (Hp * Wp);
    int i = rem / Wp;
    int j = rem - i * Wp;
    int n = nc / NLEV;
    float lo = cst.lo[n], inv = cst.inv[n];
    const size_t cb = (size_t)nc * ((size_t)H * W);
    float sx = 0.f, sy = 0.f;
    #pragma unroll
    for (int dr = -1; dr <= 0; ++dr) {
      int r = 2 * i + dr;
      if (r < 0) continue;
      const float2* x2 = reinterpret_cast<const float2*>(x + cb + (size_t)r * W);
      const float2* y2 = reinterpret_cast<const float2*>(y + cb + (size_t)r * W);
      float2 xv = x2[j], yv = y2[j];
      float xr0 = fminf(fmaxf((xv.x - lo) * inv, 0.f), 1.f);
      float xr1 = fminf(fmaxf((xv.y - lo) * inv, 0.f), 1.f);
      float yr0 = fminf(fmaxf((yv.x - lo) * inv, 0.f), 1.f);
      float yr1 = fminf(fmaxf((yv.y - lo) * inv, 0.f), 1.f);
      float w0 = __expf(5.f * yr0 * yr0 * yr0) + 1.f;
      float w1 = __expf(5.f * yr1 * yr1 * yr1) + 1.f;
      float d0 = xr0 - yr0, d1 = xr1 - yr1;
      s1 += w0 * fabsf(d0) + w1 * fabsf(d1);
      s2 += (1.f - w0) * d0 * d0 + (1.f - w1) * d1 * d1;
      sx += xr0 + xr1;
      sy += yr0 + yr1;
    }
    px[idx] = __float2bfloat16(sx * 0.25f);
    py[idx] = __float2bfloat16(sy * 0.25f);
  }
  // block reduce (wave shuffle then cross-wave via LDS)
  #pragma unroll
  for (int o = 32; o > 0; o >>= 1) { s1 += __shfl_down(s1, o); s2 += __shfl_down(s2, o); }
  __shared__ float ra[4], rb[4];
  int lane = threadIdx.x & 63, wid = threadIdx.x >> 6;
  if (lane == 0) { ra[wid] = s1; rb[wid] = s2; }
  __syncthreads();
  if (threadIdx.x == 0) {
    part[blockIdx.x] = make_float2(ra[0] + ra[1] + ra[2] + ra[3],
                                   rb[0] + rb[1] + rb[2] + rb[3]);
  }
}

// ---------------------------------------------------------------------------
// Generic 2x2 avg-pool for deeper scales (odd H -> zero pad row -1).
// ---------------------------------------------------------------------------
template <typename Tin>
__global__ __launch_bounds__(256)
void k_pool(const Tin* __restrict__ x, const Tin* __restrict__ y,
            float* __restrict__ px, float* __restrict__ py,
            int H, int W, int Hp, int Wp)
{
  int idx = blockIdx.x * 256 + threadIdx.x;
  int total = NCH * Hp * Wp;
  if (idx >= total) return;
  int nc  = idx / (Hp * Wp);
  int rem = idx - nc * (Hp * Wp);
  int i = rem / Wp;
  int j = rem - i * Wp;
  const Tin* xc = x + (size_t)nc * ((size_t)H * W);
  const Tin* yc = y + (size_t)nc * ((size_t)H * W);
  float sx = 0.f, sy = 0.f;
  #pragma unroll
  for (int dr = -1; dr <= 0; ++dr) {
    int r = 2 * i + dr;
    if (r < 0) continue;
    size_t o = (size_t)r * W + 2 * j;
    sx += (float)xc[o] + (float)xc[o + 1];
    sy += (float)yc[o] + (float)yc[o + 1];
  }
  px[idx] = sx * 0.25f;
  py[idx] = sy * 0.25f;
}

// ---------------------------------------------------------------------------
// SSIM tile kernel. Output tile 32x32 per block (256 threads). Stages a 42x42
// input tile (x,y) in LDS, vertical 11-tap pass into 5 field buffers
// (mu1,mu2,xx,yy,xy; row stride 43 -> <=2-way LDS bank aliasing, free), then
// horizontal 11-tap pass with 4 outputs/thread. Per-block cs/ssim sums written
// as float2 partials (deterministic two-stage reduction, no fp atomics).
// ---------------------------------------------------------------------------
template <typename Tin, bool NORM>
__global__ __launch_bounds__(256)
void k_ssim(const Tin* __restrict__ X, const Tin* __restrict__ Y,
            int H, int W, int Ho, int Wo,
            float2* __restrict__ part, Consts cst)
{
  constexpr int TH = 32, TW = 32, IH = 42, IW = 42, LDW = 43;
  const float C1 = 1e-4f, C2 = 9e-4f;
  __shared__ float sx[IH * LDW];
  __shared__ float sy[IH * LDW];
  __shared__ float vf[5][TH * LDW];

  int nc = blockIdx.z;
  int tr = blockIdx.y * TH;
  int tc = blockIdx.x * TW;
  int n = nc / NLEV;
  float lo = NORM ? cst.lo[n] : 0.f;
  float inv = NORM ? cst.inv[n] : 1.f;
  const Tin* Xc = X + (size_t)nc * ((size_t)H * W);
  const Tin* Yc = Y + (size_t)nc * ((size_t)H * W);

  // stage input tile (zero-fill OOB; OOB values only feed invalid outputs)
  for (int p = threadIdx.x; p < IH * IW; p += 256) {
    int r = p / IW, c = p - (p / IW) * IW;
    int gr = tr + r, gc = tc + c;
    float xv = 0.f, yv = 0.f;
    if (gr < H && gc < W) {
      size_t o = (size_t)gr * W + gc;
      xv = (float)Xc[o];
      yv = (float)Yc[o];
      if (NORM) {
        xv = fminf(fmaxf((xv - lo) * inv, 0.f), 1.f);
        yv = fminf(fmaxf((yv - lo) * inv, 0.f), 1.f);
      }
    }
    sx[r * LDW + c] = xv;
    sy[r * LDW + c] = yv;
  }
  __syncthreads();

  // vertical pass: 32 rows x 42 cols of vertically-filtered fields
  for (int p = threadIdx.x; p < TH * IW; p += 256) {
    int vr = p / IW, c = p - (p / IW) * IW;
    float ax = 0.f, ay = 0.f, axx = 0.f, ayy = 0.f, axy = 0.f;
    #pragma unroll
    for (int k = 0; k < 11; ++k) {
      float w = cst.w[k];
      float xv = sx[(vr + k) * LDW + c];
      float yv = sy[(vr + k) * LDW + c];
      ax  = fmaf(w, xv, ax);
      ay  = fmaf(w, yv, ay);
      axx = fmaf(w * xv, xv, axx);
      ayy = fmaf(w * yv, yv, ayy);
      axy = fmaf(w * xv, yv, axy);
    }
    int o = vr * LDW + c;
    vf[0][o] = ax; vf[1][o] = ay; vf[2][o] = axx; vf[3][o] = ayy; vf[4][o] = axy;
  }
  __syncthreads();

  // horizontal pass: 32 rows x 8 groups of 4 cols; 14 LDS reads per field
  float csv = 0.f, ssv = 0.f;
  {
    int orow = threadIdx.x >> 3;
    int oc0  = (threadIdx.x & 7) * 4;
    int gr = tr + orow;
    float o0[5], o1[5], o2[5], o3[5];
    #pragma unroll
    for (int f = 0; f < 5; ++f) {
      const float* row = &vf[f][orow * LDW + oc0];
      float v[14];
      #pragma unroll
      for (int k = 0; k < 14; ++k) v[k] = row[k];
      float a0 = 0.f, a1 = 0.f, a2 = 0.f, a3 = 0.f;
      #pragma unroll
      for (int k = 0; k < 11; ++k) {
        float w = cst.w[k];
        a0 = fmaf(w, v[k],     a0);
        a1 = fmaf(w, v[k + 1], a1);
        a2 = fmaf(w, v[k + 2], a2);
        a3 = fmaf(w, v[k + 3], a3);
      }
      o0[f] = a0; o1[f] = a1; o2[f] = a2; o3[f] = a3;
    }
    #pragma unroll
    for (int m = 0; m < 4; ++m) {
      const float* o = (m == 0) ? o0 : (m == 1) ? o1 : (m == 2) ? o2 : o3;
      if (gr < Ho && (tc + oc0 + m) < Wo) {
        float mu1 = o[0], mu2 = o[1], exx = o[2], eyy = o[3], exy = o[4];
        float mu1s = mu1 * mu1, mu2s = mu2 * mu2, m12 = mu1 * mu2;
        float sg1 = exx - mu1s, sg2 = eyy - mu2s, sg12 = exy - m12;
        float cs = (2.f * sg12 + C2) / (sg1 + sg2 + C2);
        float ss = (2.f * m12 + C1) / (mu1s + mu2s + C1) * cs;
        csv += cs;
        ssv += ss;
      }
    }
  }
  #pragma unroll
  for (int o = 32; o > 0; o >>= 1) { csv += __shfl_down(csv, o); ssv += __shfl_down(ssv, o); }
  __shared__ float ra[4], rb[4];
  int lane = threadIdx.x & 63, wid = threadIdx.x >> 6;
  if (lane == 0) { ra[wid] = csv; rb[wid] = ssv; }
  __syncthreads();
  if (threadIdx.x == 0) {
    int tilesPerCh = gridDim.x * gridDim.y;
    int t = blockIdx.y * gridDim.x + blockIdx.x;
    part[(size_t)nc * tilesPerCh + t] =
        make_float2(ra[0] + ra[1] + ra[2] + ra[3], rb[0] + rb[1] + rb[2] + rb[3]);
  }
}

// ---------------------------------------------------------------------------
// Reduction kernels (deterministic, fp64 accumulation).
// ---------------------------------------------------------------------------
__global__ __launch_bounds__(256)
void k_reduce_pix(const float2* __restrict__ part, int n, double* __restrict__ acc)
{
  double a = 0.0, b = 0.0;
  for (int i = threadIdx.x; i < n; i += 256) { float2 v = part[i]; a += v.x; b += v.y; }
  __shared__ double sa[256], sb[256];
  sa[threadIdx.x] = a; sb[threadIdx.x] = b;
  __syncthreads();
  for (int o = 128; o > 0; o >>= 1) {
    if (threadIdx.x < o) { sa[threadIdx.x] += sa[threadIdx.x + o]; sb[threadIdx.x] += sb[threadIdx.x + o]; }
    __syncthreads();
  }
  if (threadIdx.x == 0) { acc[0] = sa[0]; acc[1] = sb[0]; }
}

__global__ __launch_bounds__(256)
void k_reduce_ssim(const float2* __restrict__ part, int tiles,
                   double* __restrict__ cs_out, double* __restrict__ ss_out)
{
  int nc = blockIdx.x;
  const float2* p = part + (size_t)nc * tiles;
  double a = 0.0, b = 0.0;
  for (int i = threadIdx.x; i < tiles; i += 256) { float2 v = p[i]; a += v.x; b += v.y; }
  __shared__ double sa[256], sb[256];
  sa[threadIdx.x] = a; sb[threadIdx.x] = b;
  __syncthreads();
  for (int o = 128; o > 0; o >>= 1) {
    if (threadIdx.x < o) { sa[threadIdx.x] += sa[threadIdx.x + o]; sb[threadIdx.x] += sb[threadIdx.x + o]; }
    __syncthreads();
  }
  if (threadIdx.x == 0) { cs_out[nc] = sa[0]; ss_out[nc] = sb[0]; }
}

// ---------------------------------------------------------------------------
// Finalize: per-channel ms = prod_s relu(mean_s)^w_s ; loss = (1 - mean(ms))
// + 0.5*(sum1+sum2)/Ntot.
// acc layout: [0]=pix1 [1]=pix2 [2+s*117+nc]=cs [2+585+s*117+nc]=ssim
// ---------------------------------------------------------------------------
__global__ __launch_bounds__(128)
void k_final(const double* __restrict__ acc, float* __restrict__ out)
{
  const double msw[5]  = {0.0448, 0.2856, 0.3001, 0.2363, 0.1333};
  const double npix[5] = {711.0 * 1430.0, 351.0 * 710.0, 171.0 * 350.0,
                          81.0 * 170.0, 36.0 * 80.0};
  __shared__ double sh[128];
  double local = 0.0;
  for (int nc = threadIdx.x; nc < NCH; nc += 128) {
    double ms = 1.0;
    #pragma unroll
    for (int s = 0; s < 5; ++s) {
      double v = (s < 4) ? acc[2 + s * NCH + nc] : acc[2 + 5 * NCH + 4 * NCH + nc];
      v /= npix[s];
      if (v < 0.0) v = 0.0;
      ms *= pow(v, msw[s]);
    }
    local += ms;
  }
  sh[threadIdx.x] = local;
  __syncthreads();
  for (int o = 64; o > 0; o >>= 1) {
    if (threadIdx.x < o) sh[threadIdx.x] += sh[threadIdx.x + o];
    __syncthreads();
  }
  if (threadIdx.x == 0) {
    double ssim_loss = 1.0 - sh[0] / 117.0;
    const double Ntot = 9.0 * 13.0 * 721.0 * 1440.0;
    double pixel = 0.5 * (acc[0] + acc[1]) / Ntot;
    out[0] = (float)(ssim_loss + pixel);
  }
}

// ---------------------------------------------------------------------------
extern "C" void kernel_launch(void* const* d_in, const int* in_sizes, int n_in,
                              void* d_out, int out_size, void* d_ws, size_t ws_size,
                              hipStream_t stream)
{
  const float* x = (const float*)d_in[0];
  const float* y = (const float*)d_in[1];
  float* out = (float*)d_out;
  char* base = (char*)d_ws;
  const Consts cst = make_consts();

  // scale dims (input H,W per scale); Ho=H-10, Wo=W-10
  const int HS[5] = {721, 361, 181, 91, 46};
  const int WS[5] = {1440, 720, 360, 180, 90};
  int tx[5], ty[5];
  for (int s = 0; s < 5; ++s) {
    tx[s] = (WS[s] - 10 + 31) / 32;
    ty[s] = (HS[s] - 10 + 31) / 32;
  }

  // workspace layout
  double* acc = (double*)base;                       // 1172 doubles
  size_t off = 16384;
  const int NB0 = (NCH * 361 * 720 + 255) / 256;     // pool0 blocks
  float2* pix_part = (float2*)(base + off); off += (size_t)NB0 * sizeof(float2);
  off = (off + 255) & ~(size_t)255;
  float2* ss_part[5];
  for (int s = 0; s < 5; ++s) {
    ss_part[s] = (float2*)(base + off);
    off += (size_t)NCH * tx[s] * ty[s] * sizeof(float2);
    off = (off + 255) & ~(size_t)255;
  }
  // pyramid: scale1 in bf16 (big), scales 2-4 in fp32
  size_t n1 = (size_t)NCH * 361 * 720;
  size_t n2 = (size_t)NCH * 181 * 360;
  size_t n3 = (size_t)NCH * 91 * 180;
  size_t n4 = (size_t)NCH * 46 * 90;
  __hip_bfloat16* bx1 = (__hip_bfloat16*)(base + off); off += n1 * 2;
  __hip_bfloat16* by1 = (__hip_bfloat16*)(base + off); off += n1 * 2;
  off = (off + 255) & ~(size_t)255;
  float* fx2 = (float*)(base + off); off += n2 * 4;
  float* fy2 = (float*)(base + off); off += n2 * 4;
  float* fx3 = (float*)(base + off); off += n3 * 4;
  float* fy3 = (float*)(base + off); off += n3 * 4;
  float* fx4 = (float*)(base + off); off += n4 * 4;
  float* fy4 = (float*)(base + off); off += n4 * 4;
  (void)ws_size; (void)in_sizes; (void)n_in; (void)out_size;

  // 1. fused pixel loss + pool scale0->1 (bf16 pyramid)
  k_pool0<<<NB0, 256, 0, stream>>>(x, y, bx1, by1, pix_part, cst);
  k_reduce_pix<<<1, 256, 0, stream>>>(pix_part, NB0, acc);

  // 2. ssim per scale + pooling chain
  {
    dim3 g(tx[0], ty[0], NCH);
    k_ssim<float, true><<<g, 256, 0, stream>>>(x, y, 721, 1440, 711, 1430, ss_part[0], cst);
  }
  {
    dim3 g(tx[1], ty[1], NCH);
    k_ssim<__hip_bfloat16, false><<<g, 256, 0, stream>>>(bx1, by1, 361, 720, 351, 710, ss_part[1], cst);
  }
  {
    int total = NCH * 181 * 360;
    k_pool<__hip_bfloat16><<<(total + 255) / 256, 256, 0, stream>>>(bx1, by1, fx2, fy2, 361, 720, 181, 360);
  }
  {
    dim3 g(tx[2], ty[2], NCH);
    k_ssim<float, false><<<g, 256, 0, stream>>>(fx2, fy2, 181, 360, 171, 350, ss_part[2], cst);
  }
  {
    int total = NCH * 91 * 180;
    k_pool<float><<<(total + 255) / 256, 256, 0, stream>>>(fx2, fy2, fx3, fy3, 181, 360, 91, 180);
  }
  {
    dim3 g(tx[3], ty[3], NCH);
    k_ssim<float, false><<<g, 256, 0, stream>>>(fx3, fy3, 91, 180, 81, 170, ss_part[3], cst);
  }
  {
    int total = NCH * 46 * 90;
    k_pool<float><<<(total + 255) / 256, 256, 0, stream>>>(fx3, fy3, fx4, fy4, 91, 180, 46, 90);
  }
  {
    dim3 g(tx[4], ty[4], NCH);
    k_ssim<float, false><<<g, 256, 0, stream>>>(fx4, fy4, 46, 90, 36, 80, ss_part[4], cst);
  }

  // 3. reduce ssim partials per scale into acc
  for (int s = 0; s < 5; ++s) {
    k_reduce_ssim<<<NCH, 256, 0, stream>>>(ss_part[s], tx[s] * ty[s],
                                           acc + 2 + s * NCH,
                                           acc + 2 + 5 * NCH + s * NCH);
  }

  // 4. finalize
  k_final<<<1, 128, 0, stream>>>(acc, out);
}

// Round 2
// 2687.538 us; speedup vs baseline: 1.0646x; 1.0646x over previous
//
#include <hip/hip_runtime.h>
#include <hip/hip_bf16.h>
#include <cmath>

#define NCH 117   // 9*13
#define NLEV 13

struct Consts {
  float lo[9];
  float inv[9];
  float w[11];
};

static Consts make_consts() {
  static const double rmin[9] = {170.0, 85000.0, -110.0, -80.0, 170.0, 0.0, -110.0, -100.0, -1000.0};
  static const double rmax[9] = {350.0, 110000.0, 110.0, 80.0, 350.0, 0.04, 110.0, 100.0, 60000.0};
  Consts c;
  for (int i = 0; i < 9; ++i) {
    float lo = (float)rmin[i];
    float hi = (float)rmax[i];
    c.lo[i] = lo;
    c.inv[i] = (float)(1.0 / (double)(hi - lo));
  }
  double g[11], s = 0.0;
  for (int k = 0; k < 11; ++k) {
    double d = (double)k - 5.0;
    g[k] = std::exp(-d * d / 4.5);
    s += g[k];
  }
  for (int k = 0; k < 11; ++k) c.w[k] = (float)(g[k] / s);
  return c;
}

// ---------------------------------------------------------------------------
// Kernel 1: fused pixel-loss partial sums + first 2x2 avg-pool (scale0->1).
// ---------------------------------------------------------------------------
__global__ __launch_bounds__(256)
void k_pool0(const float* __restrict__ x, const float* __restrict__ y,
             __hip_bfloat16* __restrict__ px, __hip_bfloat16* __restrict__ py,
             float2* __restrict__ part, Consts cst)
{
  const int H = 721, W = 1440, Hp = 361, Wp = 720;
  int idx = blockIdx.x * 256 + threadIdx.x;
  const int total = NCH * Hp * Wp;
  float s1 = 0.f, s2 = 0.f;
  if (idx < total) {
    int nc  = idx / (Hp * Wp);
    int rem = idx - nc * (Hp * Wp);
    int i = rem / Wp;
    int j = rem - i * Wp;
    int n = nc / NLEV;
    float lo = cst.lo[n], inv = cst.inv[n];
    const size_t cb = (size_t)nc * ((size_t)H * W);
    float sx = 0.f, sy = 0.f;
    #pragma unroll
    for (int dr = -1; dr <= 0; ++dr) {
      int r = 2 * i + dr;
      if (r < 0) continue;
      const float2* x2 = reinterpret_cast<const float2*>(x + cb + (size_t)r * W);
      const float2* y2 = reinterpret_cast<const float2*>(y + cb + (size_t)r * W);
      float2 xv = x2[j], yv = y2[j];
      float xr0 = fminf(fmaxf((xv.x - lo) * inv, 0.f), 1.f);
      float xr1 = fminf(fmaxf((xv.y - lo) * inv, 0.f), 1.f);
      float yr0 = fminf(fmaxf((yv.x - lo) * inv, 0.f), 1.f);
      float yr1 = fminf(fmaxf((yv.y - lo) * inv, 0.f), 1.f);
      float w0 = __expf(5.f * yr0 * yr0 * yr0) + 1.f;
      float w1 = __expf(5.f * yr1 * yr1 * yr1) + 1.f;
      float d0 = xr0 - yr0, d1 = xr1 - yr1;
      s1 += w0 * fabsf(d0) + w1 * fabsf(d1);
      s2 += (1.f - w0) * d0 * d0 + (1.f - w1) * d1 * d1;
      sx += xr0 + xr1;
      sy += yr0 + yr1;
    }
    px[idx] = __float2bfloat16(sx * 0.25f);
    py[idx] = __float2bfloat16(sy * 0.25f);
  }
  #pragma unroll
  for (int o = 32; o > 0; o >>= 1) { s1 += __shfl_down(s1, o); s2 += __shfl_down(s2, o); }
  __shared__ float ra[4], rb[4];
  int lane = threadIdx.x & 63, wid = threadIdx.x >> 6;
  if (lane == 0) { ra[wid] = s1; rb[wid] = s2; }
  __syncthreads();
  if (threadIdx.x == 0) {
    part[blockIdx.x] = make_float2(ra[0] + ra[1] + ra[2] + ra[3],
                                   rb[0] + rb[1] + rb[2] + rb[3]);
  }
}

// ---------------------------------------------------------------------------
// Generic 2x2 avg-pool for deeper scales.
// ---------------------------------------------------------------------------
template <typename Tin>
__global__ __launch_bounds__(256)
void k_pool(const Tin* __restrict__ x, const Tin* __restrict__ y,
            float* __restrict__ px, float* __restrict__ py,
            int H, int W, int Hp, int Wp)
{
  int idx = blockIdx.x * 256 + threadIdx.x;
  int total = NCH * Hp * Wp;
  if (idx >= total) return;
  int nc  = idx / (Hp * Wp);
  int rem = idx - nc * (Hp * Wp);
  int i = rem / Wp;
  int j = rem - i * Wp;
  const Tin* xc = x + (size_t)nc * ((size_t)H * W);
  const Tin* yc = y + (size_t)nc * ((size_t)H * W);
  float sx = 0.f, sy = 0.f;
  #pragma unroll
  for (int dr = -1; dr <= 0; ++dr) {
    int r = 2 * i + dr;
    if (r < 0) continue;
    size_t o = (size_t)r * W + 2 * j;
    sx += (float)xc[o] + (float)xc[o + 1];
    sy += (float)yc[o] + (float)yc[o + 1];
  }
  px[idx] = sx * 0.25f;
  py[idx] = sy * 0.25f;
}

// ---------------------------------------------------------------------------
// SSIM row-walking column-strip kernel.
// Block = 256 threads = 256 input columns = 246 output columns (halo fits
// exactly: 246 + 10 = 256). Walk RS+10 input rows. Per row:
//   - stage float2(x,y) row into 2-row ping-pong LDS (1 b64 write)
//   - horizontal 11-tap from LDS (11 b64 reads, products on the fly)
//   - vertical via 11-slot statically-indexed scatter accumulator:
//     row loop unrolled by 11 so slot/tap indices are compile-time (55 fma,
//     no register shifting, no div/mod).
// Output row (it-10) finalizes at iteration it; its slot is then zeroed and
// immediately reused for row (it+1).
// ---------------------------------------------------------------------------
template <typename Tin, bool NORM, int RS = 100>
__global__ __launch_bounds__(256)
void k_ssim(const Tin* __restrict__ X, const Tin* __restrict__ Y,
            int H, int W, int Ho, int Wo,
            float2* __restrict__ part, Consts cst)
{
  const float C1 = 1e-4f, C2 = 9e-4f;
  __shared__ float2 sxy[2][256];

  const int tid = threadIdx.x;
  const int nc = blockIdx.z;
  const int c0 = blockIdx.x * 246;
  const int r0 = blockIdx.y * RS;
  const int n_out = min(RS, Ho - r0);
  const int iters = n_out + 10;
  const int ci = c0 + tid;
  const bool in_col = ci < W;
  const bool do_out = (tid < 246) && (ci < Wo);

  const int n = nc / NLEV;
  const float lo = NORM ? cst.lo[n] : 0.f;
  const float inv = NORM ? cst.inv[n] : 1.f;
  const Tin* Xc = X + (size_t)nc * ((size_t)H * W);
  const Tin* Yc = Y + (size_t)nc * ((size_t)H * W);
  size_t off = (size_t)r0 * W + (size_t)(in_col ? ci : 0);

  float acc0[11], acc1[11], acc2[11], acc3[11], acc4[11];
  #pragma unroll
  for (int s = 0; s < 11; ++s) { acc0[s] = 0.f; acc1[s] = 0.f; acc2[s] = 0.f; acc3[s] = 0.f; acc4[s] = 0.f; }
  float csv = 0.f, ssv = 0.f;

  for (int itb = 0; itb < iters; itb += 11) {
    #pragma unroll
    for (int u = 0; u < 11; ++u) {
      const int it = itb + u;
      if (it < iters) {                       // block-uniform predicate
        float xv = 0.f, yv = 0.f;
        if (in_col) {
          xv = (float)Xc[off];
          yv = (float)Yc[off];
          if (NORM) {
            xv = fminf(fmaxf((xv - lo) * inv, 0.f), 1.f);
            yv = fminf(fmaxf((yv - lo) * inv, 0.f), 1.f);
          }
        }
        off += W;
        const int buf = it & 1;
        sxy[buf][tid] = make_float2(xv, yv);
        __syncthreads();
        if (do_out) {
          float hx = 0.f, hy = 0.f, hxx = 0.f, hyy = 0.f, hxy = 0.f;
          #pragma unroll
          for (int k = 0; k < 11; ++k) {
            float2 v = sxy[buf][tid + k];
            float w = cst.w[k];
            float wx = w * v.x, wy = w * v.y;
            hx  = fmaf(w, v.x, hx);
            hy  = fmaf(w, v.y, hy);
            hxx = fmaf(wx, v.x, hxx);
            hyy = fmaf(wy, v.y, hyy);
            hxy = fmaf(wx, v.y, hxy);
          }
          #pragma unroll
          for (int s = 0; s < 11; ++s) {
            const float wk = cst.w[(u - s + 11) % 11];   // compile-time index
            acc0[s] = fmaf(wk, hx,  acc0[s]);
            acc1[s] = fmaf(wk, hy,  acc1[s]);
            acc2[s] = fmaf(wk, hxx, acc2[s]);
            acc3[s] = fmaf(wk, hyy, acc3[s]);
            acc4[s] = fmaf(wk, hxy, acc4[s]);
          }
          const int sd = (u + 1) % 11;                   // compile-time
          if (it >= 10 && (it - 10) < n_out) {
            float mu1 = acc0[sd], mu2 = acc1[sd];
            float exx = acc2[sd], eyy = acc3[sd], exy = acc4[sd];
            float mu1s = mu1 * mu1, mu2s = mu2 * mu2, m12 = mu1 * mu2;
            float sg1 = exx - mu1s, sg2 = eyy - mu2s, sg12 = exy - m12;
            float cs = (2.f * sg12 + C2) / (sg1 + sg2 + C2);
            float ss = (2.f * m12 + C1) / (mu1s + mu2s + C1) * cs;
            csv += cs;
            ssv += ss;
          }
          acc0[sd] = 0.f; acc1[sd] = 0.f; acc2[sd] = 0.f; acc3[sd] = 0.f; acc4[sd] = 0.f;
        }
      }
    }
  }

  #pragma unroll
  for (int o = 32; o > 0; o >>= 1) { csv += __shfl_down(csv, o); ssv += __shfl_down(ssv, o); }
  __shared__ float ra[4], rb[4];
  int lane = tid & 63, wid = tid >> 6;
  if (lane == 0) { ra[wid] = csv; rb[wid] = ssv; }
  __syncthreads();
  if (tid == 0) {
    int tilesPerCh = gridDim.x * gridDim.y;
    int t = blockIdx.y * gridDim.x + blockIdx.x;
    part[(size_t)nc * tilesPerCh + t] =
        make_float2(ra[0] + ra[1] + ra[2] + ra[3], rb[0] + rb[1] + rb[2] + rb[3]);
  }
}

// ---------------------------------------------------------------------------
// Reductions (deterministic, fp64).
// ---------------------------------------------------------------------------
__global__ __launch_bounds__(256)
void k_reduce_pix(const float2* __restrict__ part, int n, double* __restrict__ acc)
{
  double a = 0.0, b = 0.0;
  for (int i = threadIdx.x; i < n; i += 256) { float2 v = part[i]; a += v.x; b += v.y; }
  __shared__ double sa[256], sb[256];
  sa[threadIdx.x] = a; sb[threadIdx.x] = b;
  __syncthreads();
  for (int o = 128; o > 0; o >>= 1) {
    if (threadIdx.x < o) { sa[threadIdx.x] += sa[threadIdx.x + o]; sb[threadIdx.x] += sb[threadIdx.x + o]; }
    __syncthreads();
  }
  if (threadIdx.x == 0) { acc[0] = sa[0]; acc[1] = sb[0]; }
}

__global__ __launch_bounds__(256)
void k_reduce_ssim(const float2* __restrict__ part, int tiles,
                   double* __restrict__ cs_out, double* __restrict__ ss_out)
{
  int nc = blockIdx.x;
  const float2* p = part + (size_t)nc * tiles;
  double a = 0.0, b = 0.0;
  for (int i = threadIdx.x; i < tiles; i += 256) { float2 v = p[i]; a += v.x; b += v.y; }
  __shared__ double sa[256], sb[256];
  sa[threadIdx.x] = a; sb[threadIdx.x] = b;
  __syncthreads();
  for (int o = 128; o > 0; o >>= 1) {
    if (threadIdx.x < o) { sa[threadIdx.x] += sa[threadIdx.x + o]; sb[threadIdx.x] += sb[threadIdx.x + o]; }
    __syncthreads();
  }
  if (threadIdx.x == 0) { cs_out[nc] = sa[0]; ss_out[nc] = sb[0]; }
}

// ---------------------------------------------------------------------------
// Finalize.
// ---------------------------------------------------------------------------
__global__ __launch_bounds__(128)
void k_final(const double* __restrict__ acc, float* __restrict__ out)
{
  const double msw[5]  = {0.0448, 0.2856, 0.3001, 0.2363, 0.1333};
  const double npix[5] = {711.0 * 1430.0, 351.0 * 710.0, 171.0 * 350.0,
                          81.0 * 170.0, 36.0 * 80.0};
  __shared__ double sh[128];
  double local = 0.0;
  for (int nc = threadIdx.x; nc < NCH; nc += 128) {
    double ms = 1.0;
    #pragma unroll
    for (int s = 0; s < 5; ++s) {
      double v = (s < 4) ? acc[2 + s * NCH + nc] : acc[2 + 5 * NCH + 4 * NCH + nc];
      v /= npix[s];
      if (v < 0.0) v = 0.0;
      ms *= pow(v, msw[s]);
    }
    local += ms;
  }
  sh[threadIdx.x] = local;
  __syncthreads();
  for (int o = 64; o > 0; o >>= 1) {
    if (threadIdx.x < o) sh[threadIdx.x] += sh[threadIdx.x + o];
    __syncthreads();
  }
  if (threadIdx.x == 0) {
    double ssim_loss = 1.0 - sh[0] / 117.0;
    const double Ntot = 9.0 * 13.0 * 721.0 * 1440.0;
    double pixel = 0.5 * (acc[0] + acc[1]) / Ntot;
    out[0] = (float)(ssim_loss + pixel);
  }
}

// ---------------------------------------------------------------------------
extern "C" void kernel_launch(void* const* d_in, const int* in_sizes, int n_in,
                              void* d_out, int out_size, void* d_ws, size_t ws_size,
                              hipStream_t stream)
{
  const float* x = (const float*)d_in[0];
  const float* y = (const float*)d_in[1];
  float* out = (float*)d_out;
  char* base = (char*)d_ws;
  const Consts cst = make_consts();
  const int RS = 100;

  const int HS[5] = {721, 361, 181, 91, 46};
  const int WS[5] = {1440, 720, 360, 180, 90};
  int tx[5], ty[5];
  for (int s = 0; s < 5; ++s) {
    int Ho = HS[s] - 10, Wo = WS[s] - 10;
    tx[s] = (Wo + 245) / 246;
    ty[s] = (Ho + RS - 1) / RS;
  }

  double* acc = (double*)base;
  size_t off = 16384;
  const int NB0 = (NCH * 361 * 720 + 255) / 256;
  float2* pix_part = (float2*)(base + off); off += (size_t)NB0 * sizeof(float2);
  off = (off + 255) & ~(size_t)255;
  float2* ss_part[5];
  for (int s = 0; s < 5; ++s) {
    ss_part[s] = (float2*)(base + off);
    off += (size_t)NCH * tx[s] * ty[s] * sizeof(float2);
    off = (off + 255) & ~(size_t)255;
  }
  size_t n1 = (size_t)NCH * 361 * 720;
  size_t n2 = (size_t)NCH * 181 * 360;
  size_t n3 = (size_t)NCH * 91 * 180;
  size_t n4 = (size_t)NCH * 46 * 90;
  __hip_bfloat16* bx1 = (__hip_bfloat16*)(base + off); off += n1 * 2;
  __hip_bfloat16* by1 = (__hip_bfloat16*)(base + off); off += n1 * 2;
  off = (off + 255) & ~(size_t)255;
  float* fx2 = (float*)(base + off); off += n2 * 4;
  float* fy2 = (float*)(base + off); off += n2 * 4;
  float* fx3 = (float*)(base + off); off += n3 * 4;
  float* fy3 = (float*)(base + off); off += n3 * 4;
  float* fx4 = (float*)(base + off); off += n4 * 4;
  float* fy4 = (float*)(base + off); off += n4 * 4;
  (void)ws_size; (void)in_sizes; (void)n_in; (void)out_size;

  k_pool0<<<NB0, 256, 0, stream>>>(x, y, bx1, by1, pix_part, cst);
  k_reduce_pix<<<1, 256, 0, stream>>>(pix_part, NB0, acc);

  {
    dim3 g(tx[0], ty[0], NCH);
    k_ssim<float, true><<<g, 256, 0, stream>>>(x, y, 721, 1440, 711, 1430, ss_part[0], cst);
  }
  {
    dim3 g(tx[1], ty[1], NCH);
    k_ssim<__hip_bfloat16, false><<<g, 256, 0, stream>>>(bx1, by1, 361, 720, 351, 710, ss_part[1], cst);
  }
  {
    int total = NCH * 181 * 360;
    k_pool<__hip_bfloat16><<<(total + 255) / 256, 256, 0, stream>>>(bx1, by1, fx2, fy2, 361, 720, 181, 360);
  }
  {
    dim3 g(tx[2], ty[2], NCH);
    k_ssim<float, false><<<g, 256, 0, stream>>>(fx2, fy2, 181, 360, 171, 350, ss_part[2], cst);
  }
  {
    int total = NCH * 91 * 180;
    k_pool<float><<<(total + 255) / 256, 256, 0, stream>>>(fx2, fy2, fx3, fy3, 181, 360, 91, 180);
  }
  {
    dim3 g(tx[3], ty[3], NCH);
    k_ssim<float, false><<<g, 256, 0, stream>>>(fx3, fy3, 91, 180, 81, 170, ss_part[3], cst);
  }
  {
    int total = NCH * 46 * 90;
    k_pool<float><<<(total + 255) / 256, 256, 0, stream>>>(fx3, fy3, fx4, fy4, 91, 180, 46, 90);
  }
  {
    dim3 g(tx[4], ty[4], NCH);
    k_ssim<float, false><<<g, 256, 0, stream>>>(fx4, fy4, 46, 90, 36, 80, ss_part[4], cst);
  }

  for (int s = 0; s < 5; ++s) {
    k_reduce_ssim<<<NCH, 256, 0, stream>>>(ss_part[s], tx[s] * ty[s],
                                           acc + 2 + s * NCH,
                                           acc + 2 + 5 * NCH + s * NCH);
  }

  k_final<<<1, 128, 0, stream>>>(acc, out);
}